// Round 5
// baseline (360.896 us; speedup 1.0000x reference)
//
#include <hip/hip_runtime.h>
#include <hip/hip_bf16.h>

// Problem constants (SymNetDP): B=64, S=4096, NGB=13, NG=48, DIM=3, NCH={8,8,1}
#define BATCH 64
#define SITES 4096
#define NGB 13
#define NGRP 48
#define SDIM 3

typedef __bf16 bf16x8 __attribute__((ext_vector_type(8)));
typedef float  f32x4  __attribute__((ext_vector_type(4)));

// ---------------------------------------------------------------------------
// Workspace layout (floats):
//   Avc  : 39 f32 (pad 64)                      @ 0
//   U    : bf16 region, 135168 elems            @ 64
//     W0H [384][32] 12288 | W0L @12288 | W1H [384][128] @24576 (49152) |
//     W1L @73728 | W2H [48][128] @122880 (6144) | W2L @129024
//   A0H/A0L : (B,S,8) bf16 channel-last, 2097152 elems each
//   A1H/A1L : (B,S,8) bf16 channel-last
//   A2   : (B,S) f32, aliases A0H (A0 dead once L2 runs)
//   PART : (64,16,3)                            @ 4261952
// K-packing for NCIN=8 layers: k = j*8 + c  (site's 8 channels contiguous).
// v15: activations stored as bf16 hi/lo pairs in GLOBAL (split at write time,
// 13x less cvt than split-at-gather); staging via global_load_lds DMA (zero
// VALU, zero VGPR, issued async at iteration start); LDS layout [j][col][c8]
// so one DMA stages 64 sites and MFMA B-frags are 16B-contiguous (no bank
// conflicts).
// ---------------------------------------------------------------------------
#define OFF_AVC  0
#define OFF_U    64
#define OFF_A0H  67648
#define OFF_A0L  1116224
#define OFF_A1H  2164800
#define OFF_A1L  3213376
#define OFF_PART 4261952
#define UW0H 0
#define UW0L 12288
#define UW1H 24576
#define UW1L 73728
#define UW2H 122880
#define UW2L 129024

__device__ __forceinline__ float softplus_f(float h) {
    return fmaxf(h, 0.f) + __logf(1.f + __expf(-fabsf(h)));
}

// async 16B global->LDS DMA: per-lane global src, wave-uniform LDS base,
// HW writes lane l's 16B at lds + l*16 (m03/m97/m104).
__device__ __forceinline__ void gld_lds16(const __bf16* g, __bf16* l) {
    __builtin_amdgcn_global_load_lds(
        (const __attribute__((address_space(1))) void*)g,
        (__attribute__((address_space(3))) void*)l,
        16, 0, 0);
}

// ---------------------------------------------------------------------------
// Precompute: rotated weights, bf16 hi/lo split, [row=o*48+g][KPAD] with
// k = j*8+c packing for K=104 layers (k = j for layer 0); plus Avc.
// ---------------------------------------------------------------------------
__global__ __launch_bounds__(256) void precompute_kernel(
    const float* __restrict__ Psi0, const float* __restrict__ Psi1,
    const float* __restrict__ Psi2, const float* __restrict__ wtVC,
    const float* __restrict__ gdiags, const int* __restrict__ perms,
    float* __restrict__ ws)
{
    float*  Avc = ws + OFF_AVC;
    __bf16* U   = (__bf16*)(ws + OFF_U);
    int t = blockIdx.x * 256 + threadIdx.x;
    if (t < 12288) {                       // W0: [384][32], k=j
        int k = t & 31, row = t >> 5;
        int o = row / NGRP, g = row - o * NGRP;
        float w = (k < NGB) ? Psi0[o * NGB + perms[g * NGB + k]] : 0.f;
        __bf16 hi = (__bf16)w;
        U[UW0H + t] = hi;
        U[UW0L + t] = (__bf16)(w - (float)hi);
    } else if (t < 61440) {                // W1: [384][128], k=j*8+c
        int u = t - 12288;
        int k = u & 127, row = u >> 7;
        int o = row / NGRP, g = row - o * NGRP;
        float w = 0.f;
        if (k < 104) { int j = k >> 3, c = k & 7;
                       w = Psi1[(o * 8 + c) * NGB + perms[g * NGB + j]]; }
        __bf16 hi = (__bf16)w;
        U[UW1H + u] = hi;
        U[UW1L + u] = (__bf16)(w - (float)hi);
    } else if (t < 67584) {                // W2: [48][128], k=j*8+c
        int u = t - 61440;
        int k = u & 127, g = u >> 7;
        float w = 0.f;
        if (k < 104) { int j = k >> 3, c = k & 7;
                       w = Psi2[c * NGB + perms[g * NGB + j]]; }
        __bf16 hi = (__bf16)w;
        U[UW2H + u] = hi;
        U[UW2L + u] = (__bf16)(w - (float)hi);
    } else if (t < 67584 + 39 * NGRP) {    // Avc
        int t2 = t - 67584;
        int g = t2 % NGRP, u = t2 / NGRP;
        int d = u / NGB, n = u % NGB;
        const int row = g * SDIM + d;
        float s = 0.f;
        for (int k = 0; k < NGRP * SDIM; k++) {
            int g2 = k / SDIM, d2 = k - g2 * SDIM;
            float p = wtVC[d2 * NGB + perms[g2 * NGB + n]];
            s = fmaf(gdiags[row * (NGRP * SDIM) + k], p, s);
        }
        atomicAdd(&Avc[u], s * (1.f / 48.f));
    }
}

// ---------------------------------------------------------------------------
// MFMA gconv layer (bf16x3 split), v15.
// NCIN==8: input is hi/lo bf16 pairs; LDS [16][CT][8] (j-major, site's 8
// channels contiguous 16B). Staging = global_load_lds per (j, wave): lane l
// stages site col=l. Issued at iteration START into the free buffer (true
// async; the implicit vmcnt(0)+barrier drain at iteration end guarantees
// arrival before the next compute). Zero staging VALU/VGPR.
// NCIN==1 (L0): v13 path (scalar f32 gather + split), outputs hi/lo.
// ---------------------------------------------------------------------------
template<int NCIN, int NCTOT, int OUTF32, int CT, int KPAD, int KSTR,
         int NWAVES, int NWN, int CHUNKS>
__global__ __launch_bounds__(NWAVES * 64) void layer_mfma(
    const float*  __restrict__ prevF,   // (B,S) f32 (NCIN==1)
    const __bf16* __restrict__ prevH,   // (B,S,8) bf16 (NCIN==8)
    const __bf16* __restrict__ prevL,
    const __bf16* __restrict__ Wh,      // [NCTOT*48][KPAD]
    const __bf16* __restrict__ Wl,
    const float*  __restrict__ bias,    // (NCTOT,)
    const int*    __restrict__ NN,      // (13, S)
    float*  __restrict__ outF,          // (B,S) f32 (OUTF32)
    __bf16* __restrict__ outH,          // (B,S,NCTOT) bf16 (!OUTF32)
    __bf16* __restrict__ outL)
{
    constexpr int NTHR   = NWAVES * 64;
    constexpr int M      = NCTOT * NGRP;
    constexpr int MTILES = M / 16, NTILES = CT / 16;
    constexpr int NWM    = NWAVES / NWN;
    constexpr int MT_W   = MTILES / NWM, NT_W = NTILES / NWN;
    constexpr int KT     = KPAD / 32;
    constexpr int CPB    = SITES / CT;            // chunks per batch
    constexpr int BPB    = CPB / CHUNKS;          // blocks per batch
    constexpr int BUF    = (NCIN == 1) ? CT * KSTR : 16 * CT * 8; // halfwords
    constexpr int GS     = NGB * CT;
    constexpr int SPT    = (GS + NTHR - 1) / NTHR;
    constexpr int JPW    = (NGB + NWAVES - 1) / NWAVES;

    static_assert(MT_W * 16 == NGRP, "wave covers exactly one o");
    static_assert(NWM * MT_W == MTILES && NWN * NT_W == NTILES, "");
    static_assert(CPB % CHUNKS == 0, "block stays within one batch");
    static_assert(NCIN == 1 || CT == 64, "DMA staging: lane==col");

    __shared__ __bf16 xh_lds[2 * BUF];
    __shared__ __bf16 xl_lds[2 * BUF];

    const int tid  = threadIdx.x;
    const int wave = tid >> 6, lane = tid & 63;
    const int m16  = lane & 15, quad = lane >> 4;

    const int bid    = blockIdx.x;
    const int b      = bid / BPB;
    const int octet  = bid % BPB;
    const int s0base = octet * (CHUNKS * CT);

    // --- NCIN==1 staging helpers (register path) ----------------------------
    int sj[SPT], scol[SPT];
    bool sv[SPT];
#pragma unroll
    for (int i = 0; i < SPT; i++) {
        int site = tid + i * NTHR;
        sv[i] = (site < GS);
        int ss = sv[i] ? site : 0;
        sj[i] = ss / CT;
        scol[i] = ss % CT;
    }
    auto stage_site1 = [&](int i, int nn, __bf16* dh, __bf16* dl) {
        float v = prevF[(size_t)b * SITES + nn];
        __bf16 hi = (__bf16)v;
        dh[scol[i] * KSTR + sj[i]] = hi;
        dl[scol[i] * KSTR + sj[i]] = (__bf16)(v - (float)hi);
    };

    // --- zero K-pad of BOTH buffers once ------------------------------------
    if constexpr (NCIN == 1) {
        for (int e = tid; e < 2 * CT * (KPAD - NGB); e += NTHR) {
            int buf = e / (CT * (KPAD - NGB));
            int r   = e % (CT * (KPAD - NGB));
            int col = r / (KPAD - NGB), p = r % (KPAD - NGB);
            xh_lds[buf * BUF + col * KSTR + NGB + p] = (__bf16)0.f;
            xl_lds[buf * BUF + col * KSTR + NGB + p] = (__bf16)0.f;
        }
    } else {
        const bf16x8 z8 = {};
        for (int e = tid; e < 2 * 3 * CT; e += NTHR) {   // j = 13,14,15
            int buf = e / (3 * CT), r = e % (3 * CT);
            *(bf16x8*)(xh_lds + buf * BUF + (13 * CT + r) * 8) = z8;
            *(bf16x8*)(xl_lds + buf * BUF + (13 * CT + r) * 8) = z8;
        }
    }

    // --- prologue: stage chunk 0 into buffer 0; prefetch NN for chunk 1 -----
    int nnA[SPT];     // NCIN==1
    int nnP[JPW];     // NCIN==8
    if constexpr (NCIN == 1) {
#pragma unroll
        for (int i = 0; i < SPT; i++) if (sv[i]) {
            int nn = NN[sj[i] * SITES + s0base + scol[i]];
            stage_site1(i, nn, xh_lds, xl_lds);
        }
        if (CHUNKS > 1) {
            const int s1 = s0base + CT;
#pragma unroll
            for (int i = 0; i < SPT; i++)
                nnA[i] = sv[i] ? NN[sj[i] * SITES + s1 + scol[i]] : 0;
        }
    } else {
#pragma unroll
        for (int u = 0; u < JPW; u++) {
            int jj = wave + u * NWAVES;
            if (jj < NGB) {
                int nn0 = NN[jj * SITES + s0base + lane];
                gld_lds16(prevH + ((size_t)(b * SITES + nn0)) * 8, xh_lds + jj * CT * 8);
                gld_lds16(prevL + ((size_t)(b * SITES + nn0)) * 8, xl_lds + jj * CT * 8);
            }
        }
        if (CHUNKS > 1) {
#pragma unroll
            for (int u = 0; u < JPW; u++) {
                int jj = wave + u * NWAVES;
                nnP[u] = (jj < NGB) ? NN[jj * SITES + s0base + CT + lane] : 0;
            }
        }
    }
    __syncthreads();   // drains vmcnt -> chunk 0 DMA landed

    const int wave_mt0 = (wave / NWN) * MT_W;
    const int wave_nt0 = (wave % NWN) * NT_W;
    const int o_g      = (wave_mt0 * 16) / NGRP;
    const float bo     = bias[o_g];

#pragma unroll 1
    for (int c = 0; c < CHUNKS; c++) {
        const int cur = c & 1;

        // --- (1) async-stage chunk c+1 into the free buffer (NCIN==8) -------
        if constexpr (NCIN == 8) {
            if (c + 1 < CHUNKS) {
                __bf16* dh = xh_lds + (cur ^ 1) * BUF;
                __bf16* dl = xl_lds + (cur ^ 1) * BUF;
#pragma unroll
                for (int u = 0; u < JPW; u++) {
                    int jj = wave + u * NWAVES;
                    if (jj < NGB) {
                        gld_lds16(prevH + ((size_t)(b * SITES + nnP[u])) * 8, dh + jj * CT * 8);
                        gld_lds16(prevL + ((size_t)(b * SITES + nnP[u])) * 8, dl + jj * CT * 8);
                    }
                }
                if (c + 2 < CHUNKS) {
                    const int s2 = s0base + (c + 2) * CT;
#pragma unroll
                    for (int u = 0; u < JPW; u++) {
                        int jj = wave + u * NWAVES;
                        nnP[u] = (jj < NGB) ? NN[jj * SITES + s2 + lane] : 0;
                    }
                }
            }
        }

        // --- (2) compute chunk c from buffer cur ----------------------------
        const __bf16* xh = xh_lds + cur * BUF;
        const __bf16* xl = xl_lds + cur * BUF;

        f32x4 acc[MT_W][NT_W];
#pragma unroll
        for (int mt = 0; mt < MT_W; mt++)
#pragma unroll
            for (int nt = 0; nt < NT_W; nt++) acc[mt][nt] = (f32x4){0.f, 0.f, 0.f, 0.f};

#pragma unroll
        for (int kt = 0; kt < KT; kt++) {
            const int koff = kt * 32 + quad * 8;
            bf16x8 ah[MT_W], al[MT_W], bh[NT_W], bl[NT_W];
#pragma unroll
            for (int mt = 0; mt < MT_W; mt++) {
                int row = (wave_mt0 + mt) * 16 + m16;
                ah[mt] = *(const bf16x8*)(Wh + (size_t)row * KPAD + koff);
                al[mt] = *(const bf16x8*)(Wl + (size_t)row * KPAD + koff);
            }
#pragma unroll
            for (int nt = 0; nt < NT_W; nt++) {
                int cbase;
                if constexpr (NCIN == 1)
                    cbase = ((wave_nt0 + nt) * 16 + m16) * KSTR + koff;
                else
                    cbase = ((kt * 4 + quad) * CT + (wave_nt0 + nt) * 16 + m16) * 8;
                bh[nt] = *(const bf16x8*)(xh + cbase);
                bl[nt] = *(const bf16x8*)(xl + cbase);
            }
            // product-major: 12 independent MFMAs between same-acc reuse
#pragma unroll
            for (int mt = 0; mt < MT_W; mt++)
#pragma unroll
                for (int nt = 0; nt < NT_W; nt++)
                    acc[mt][nt] = __builtin_amdgcn_mfma_f32_16x16x32_bf16(
                        ah[mt], bh[nt], acc[mt][nt], 0, 0, 0);
#pragma unroll
            for (int mt = 0; mt < MT_W; mt++)
#pragma unroll
                for (int nt = 0; nt < NT_W; nt++)
                    acc[mt][nt] = __builtin_amdgcn_mfma_f32_16x16x32_bf16(
                        al[mt], bh[nt], acc[mt][nt], 0, 0, 0);
#pragma unroll
            for (int mt = 0; mt < MT_W; mt++)
#pragma unroll
                for (int nt = 0; nt < NT_W; nt++)
                    acc[mt][nt] = __builtin_amdgcn_mfma_f32_16x16x32_bf16(
                        ah[mt], bl[nt], acc[mt][nt], 0, 0, 0);
        }

        // --- (3) epilogue: softplus + group mean (one o per wave) -----------
        const int s0c = s0base + c * CT;
#pragma unroll
        for (int nt = 0; nt < NT_W; nt++) {
            float s = 0.f;
#pragma unroll
            for (int mt = 0; mt < MT_W; mt++)
#pragma unroll
                for (int r = 0; r < 4; r++)
                    s += softplus_f(acc[mt][nt][r] + bo);
            s += __shfl_xor(s, 16);
            s += __shfl_xor(s, 32);
            if (quad == 0) {
                float sv2 = s * (1.f / 48.f);
                size_t idx = (size_t)(b * SITES + s0c + (wave_nt0 + nt) * 16 + m16);
                if constexpr (OUTF32) {
                    outF[idx] = sv2;
                } else {
                    __bf16 hi = (__bf16)sv2;
                    outH[idx * NCTOT + o_g] = hi;
                    outL[idx * NCTOT + o_g] = (__bf16)(sv2 - (float)hi);
                }
            }
        }

        // --- (4) NCIN==1: stage chunk c+1 (register path, late) -------------
        if constexpr (NCIN == 1) {
            if (c + 1 < CHUNKS) {
                __bf16* dh = xh_lds + (cur ^ 1) * BUF;
                __bf16* dl = xl_lds + (cur ^ 1) * BUF;
#pragma unroll
                for (int i = 0; i < SPT; i++) if (sv[i])
                    stage_site1(i, nnA[i], dh, dl);
                if (c + 2 < CHUNKS) {
                    const int s2 = s0base + (c + 2) * CT;
#pragma unroll
                    for (int i = 0; i < SPT; i++)
                        nnA[i] = sv[i] ? NN[sj[i] * SITES + s2 + scol[i]] : 0;
                }
            }
        }
        __syncthreads();   // drains vmcnt -> chunk c+1 DMA landed
    }
}

// ---------------------------------------------------------------------------
// Reduce stage A: per (b, s-chunk) block -> 3 partial sums
// ---------------------------------------------------------------------------
__global__ __launch_bounds__(256) void reduce_a(
    const float* __restrict__ A2, const int* __restrict__ NN,
    const int* __restrict__ s2sh, const float* __restrict__ sw,
    const float* __restrict__ Avc, float* __restrict__ partial)
{
    const int b = blockIdx.x >> 4;
    const int chunk = blockIdx.x & 15;
    const int tid = threadIdx.x;
    const int s = (chunk << 8) + tid;
    const float* a = A2 + (size_t)b * SITES;

    float y0 = 0.f, y1 = 0.f, y2 = 0.f;
#pragma unroll
    for (int n = 0; n < NGB; n++) {
        float v = a[NN[n * SITES + s]];
        y0 = fmaf(Avc[n],           v, y0);
        y1 = fmaf(Avc[NGB + n],     v, y1);
        y2 = fmaf(Avc[2 * NGB + n], v, y2);
    }
    const float wgt = sw[s2sh[s]];
    y0 *= wgt; y1 *= wgt; y2 *= wgt;

    __shared__ float red[3][256];
    red[0][tid] = y0; red[1][tid] = y1; red[2][tid] = y2;
    __syncthreads();
    for (int st = 128; st > 0; st >>= 1) {
        if (tid < st) {
            red[0][tid] += red[0][tid + st];
            red[1][tid] += red[1][tid + st];
            red[2][tid] += red[2][tid + st];
        }
        __syncthreads();
    }
    if (tid < 3) partial[(b * 16 + chunk) * 3 + tid] = red[tid][0];
}

__global__ __launch_bounds__(256) void reduce_b(
    const float* __restrict__ partial, float* __restrict__ out)
{
    int t = threadIdx.x;
    if (t < BATCH * 3) {
        int b = t / 3, d = t - b * 3;
        float s = 0.f;
        for (int c = 0; c < 16; c++) s += partial[(b * 16 + c) * 3 + d];
        out[t] = s * (1.f / (float)SITES);
    }
}

// ---------------------------------------------------------------------------
extern "C" void kernel_launch(void* const* d_in, const int* in_sizes, int n_in,
                              void* d_out, int out_size, void* d_ws, size_t ws_size,
                              hipStream_t stream)
{
    const float* InStates = (const float*)d_in[0];
    const float* Psi0     = (const float*)d_in[1];
    const float* bias0    = (const float*)d_in[2];
    const float* Psi1     = (const float*)d_in[3];
    const float* bias1    = (const float*)d_in[4];
    const float* Psi2     = (const float*)d_in[5];
    const float* bias2    = (const float*)d_in[6];
    const float* wtVC     = (const float*)d_in[7];
    const float* ShellW   = (const float*)d_in[8];
    const float* gdiags   = (const float*)d_in[9];
    const int*   GnnPerms = (const int*)d_in[10];
    const int*   NNSites  = (const int*)d_in[11];
    const int*   S2Sh     = (const int*)d_in[12];

    float*  ws   = (float*)d_ws;
    float*  Avc  = ws + OFF_AVC;
    __bf16* U    = (__bf16*)(ws + OFF_U);
    __bf16* A0H  = (__bf16*)(ws + OFF_A0H);
    __bf16* A0L  = (__bf16*)(ws + OFF_A0L);
    __bf16* A1H  = (__bf16*)(ws + OFF_A1H);
    __bf16* A1L  = (__bf16*)(ws + OFF_A1L);
    float*  A2   = ws + OFF_A0H;     // f32 (B,S): A0 dead once L2 runs
    float*  PART = ws + OFF_PART;

    float* out = (float*)d_out;      // (64,3) f32

    hipMemsetAsync(Avc, 0, 64 * sizeof(float), stream);
    precompute_kernel<<<272, 256, 0, stream>>>(Psi0, Psi1, Psi2, wtVC, gdiags,
                                               GnnPerms, ws);

    constexpr int CHUNKS = 8;
    constexpr int NBLK   = BATCH * (SITES / 64) / CHUNKS;   // 512 blocks

    // L0: K=13 pad 32, KSTR=40; f32 in, hi/lo bf16 out
    layer_mfma<1, 8, 0, 64, 32, 40, 8, 1, CHUNKS><<<NBLK, 512, 0, stream>>>(
        InStates, nullptr, nullptr, U + UW0H, U + UW0L, bias0, NNSites,
        nullptr, A0H, A0L);
    // L1: K=104 pad 128; hi/lo in (DMA-staged), hi/lo out
    layer_mfma<8, 8, 0, 64, 128, 136, 8, 1, CHUNKS><<<NBLK, 512, 0, stream>>>(
        nullptr, A0H, A0L, U + UW1H, U + UW1L, bias1, NNSites,
        nullptr, A1H, A1L);
    // L2: K=104 pad 128, M=48 (1 o), 4 waves split cols; f32 out
    layer_mfma<8, 1, 1, 64, 128, 136, 4, 4, CHUNKS><<<NBLK, 256, 0, stream>>>(
        nullptr, A1H, A1L, U + UW2H, U + UW2L, bias2, NNSites,
        A2, nullptr, nullptr);

    reduce_a<<<BATCH * 16, 256, 0, stream>>>(A2, NNSites, S2Sh, ShellW, Avc, PART);
    reduce_b<<<1, 256, 0, stream>>>(PART, out);
}

// Round 6
// 354.261 us; speedup vs baseline: 1.0187x; 1.0187x over previous
//
#include <hip/hip_runtime.h>
#include <hip/hip_bf16.h>

// Problem constants (SymNetDP): B=64, S=4096, NGB=13, NG=48, DIM=3, NCH={8,8,1}
#define BATCH 64
#define SITES 4096
#define NGB 13
#define NGRP 48
#define SDIM 3

typedef __bf16 bf16x8 __attribute__((ext_vector_type(8)));
typedef float  f32x4  __attribute__((ext_vector_type(4)));

// ---------------------------------------------------------------------------
// Workspace layout (floats):
//   Avc  : 39 f32 (pad 64)                      @ 0
//   U    : bf16 region, 135168 elems            @ 64
//     W0H [384][32] 12288 | W0L @12288 | W1H [384][128] @24576 (49152) |
//     W1L @73728 | W2H [48][128] @122880 (6144) | W2L @129024
//   A0H/A0L : (B,S,8) bf16 channel-last, 2097152 elems each
//   A1H/A1L : (B,S,8) bf16 channel-last
//   A2   : (B,S) f32, aliases A0H (A0 dead once L2 runs)
//   PART : (64,16,3)                            @ 4261952
// K-packing for NCIN=8 layers: k = j*8 + c  (site's 8 channels contiguous).
//
// v16 = v13 staging mechanism + v15 data layout.
// v15 post-mortem: DMA-early staging added ~15us idle (vmcnt(0) drain at the
// barrier exposed the scatter-DMA gather latency; zero registers held means
// zero pipelining with compute). But v15's layout wins were real: bank
// conflicts 4.19M -> 0, gather bytes halved. v16 keeps hi/lo-bf16 global
// activations + [j][col][c8] LDS, and stages with v13's late register path:
// load 16B H + 16B L per (j,lane) slot, ds_write_b128 immediately, after the
// epilogue, one barrier per chunk. Only nnP[] ints cross the compute phase
// (no spill: v10-12 lesson).
// ---------------------------------------------------------------------------
#define OFF_AVC  0
#define OFF_U    64
#define OFF_A0H  67648
#define OFF_A0L  1116224
#define OFF_A1H  2164800
#define OFF_A1L  3213376
#define OFF_PART 4261952
#define UW0H 0
#define UW0L 12288
#define UW1H 24576
#define UW1L 73728
#define UW2H 122880
#define UW2L 129024

__device__ __forceinline__ float softplus_f(float h) {
    return fmaxf(h, 0.f) + __logf(1.f + __expf(-fabsf(h)));
}

// ---------------------------------------------------------------------------
// Precompute: rotated weights, bf16 hi/lo split, [row=o*48+g][KPAD] with
// k = j*8+c packing for K=104 layers (k = j for layer 0); plus Avc.
// ---------------------------------------------------------------------------
__global__ __launch_bounds__(256) void precompute_kernel(
    const float* __restrict__ Psi0, const float* __restrict__ Psi1,
    const float* __restrict__ Psi2, const float* __restrict__ wtVC,
    const float* __restrict__ gdiags, const int* __restrict__ perms,
    float* __restrict__ ws)
{
    float*  Avc = ws + OFF_AVC;
    __bf16* U   = (__bf16*)(ws + OFF_U);
    int t = blockIdx.x * 256 + threadIdx.x;
    if (t < 12288) {                       // W0: [384][32], k=j
        int k = t & 31, row = t >> 5;
        int o = row / NGRP, g = row - o * NGRP;
        float w = (k < NGB) ? Psi0[o * NGB + perms[g * NGB + k]] : 0.f;
        __bf16 hi = (__bf16)w;
        U[UW0H + t] = hi;
        U[UW0L + t] = (__bf16)(w - (float)hi);
    } else if (t < 61440) {                // W1: [384][128], k=j*8+c
        int u = t - 12288;
        int k = u & 127, row = u >> 7;
        int o = row / NGRP, g = row - o * NGRP;
        float w = 0.f;
        if (k < 104) { int j = k >> 3, c = k & 7;
                       w = Psi1[(o * 8 + c) * NGB + perms[g * NGB + j]]; }
        __bf16 hi = (__bf16)w;
        U[UW1H + u] = hi;
        U[UW1L + u] = (__bf16)(w - (float)hi);
    } else if (t < 67584) {                // W2: [48][128], k=j*8+c
        int u = t - 61440;
        int k = u & 127, g = u >> 7;
        float w = 0.f;
        if (k < 104) { int j = k >> 3, c = k & 7;
                       w = Psi2[c * NGB + perms[g * NGB + j]]; }
        __bf16 hi = (__bf16)w;
        U[UW2H + u] = hi;
        U[UW2L + u] = (__bf16)(w - (float)hi);
    } else if (t < 67584 + 39 * NGRP) {    // Avc
        int t2 = t - 67584;
        int g = t2 % NGRP, u = t2 / NGRP;
        int d = u / NGB, n = u % NGB;
        const int row = g * SDIM + d;
        float s = 0.f;
        for (int k = 0; k < NGRP * SDIM; k++) {
            int g2 = k / SDIM, d2 = k - g2 * SDIM;
            float p = wtVC[d2 * NGB + perms[g2 * NGB + n]];
            s = fmaf(gdiags[row * (NGRP * SDIM) + k], p, s);
        }
        atomicAdd(&Avc[u], s * (1.f / 48.f));
    }
}

// ---------------------------------------------------------------------------
// MFMA gconv layer (bf16x3 split), v16.
// NCIN==8: input is hi/lo bf16 pairs; LDS [16][CT][8] (j-major, site's 8
// channels contiguous 16B = one MFMA B-frag k-slice). Staging: per (j,lane)
// slot, two 16B register loads + two ds_write_b128, placed AFTER the
// epilogue (v13 ordering: latency overlapped by neighbor waves / other
// resident block, no long-lived registers).
// NCIN==1 (L0): scalar f32 gather + split (v13 path), hi/lo bf16 out.
// ---------------------------------------------------------------------------
template<int NCIN, int NCTOT, int OUTF32, int CT, int KPAD, int KSTR,
         int NWAVES, int NWN, int CHUNKS>
__global__ __launch_bounds__(NWAVES * 64) void layer_mfma(
    const float*  __restrict__ prevF,   // (B,S) f32 (NCIN==1)
    const __bf16* __restrict__ prevH,   // (B,S,8) bf16 (NCIN==8)
    const __bf16* __restrict__ prevL,
    const __bf16* __restrict__ Wh,      // [NCTOT*48][KPAD]
    const __bf16* __restrict__ Wl,
    const float*  __restrict__ bias,    // (NCTOT,)
    const int*    __restrict__ NN,      // (13, S)
    float*  __restrict__ outF,          // (B,S) f32 (OUTF32)
    __bf16* __restrict__ outH,          // (B,S,NCTOT) bf16 (!OUTF32)
    __bf16* __restrict__ outL)
{
    constexpr int NTHR   = NWAVES * 64;
    constexpr int M      = NCTOT * NGRP;
    constexpr int MTILES = M / 16, NTILES = CT / 16;
    constexpr int NWM    = NWAVES / NWN;
    constexpr int MT_W   = MTILES / NWM, NT_W = NTILES / NWN;
    constexpr int KT     = KPAD / 32;
    constexpr int CPB    = SITES / CT;            // chunks per batch
    constexpr int BPB    = CPB / CHUNKS;          // blocks per batch
    constexpr int BUF    = (NCIN == 1) ? CT * KSTR : 16 * CT * 8; // halfwords
    constexpr int GS     = NGB * CT;
    constexpr int SPT    = (GS + NTHR - 1) / NTHR;
    constexpr int JPW    = (NGB + NWAVES - 1) / NWAVES;

    static_assert(MT_W * 16 == NGRP, "wave covers exactly one o");
    static_assert(NWM * MT_W == MTILES && NWN * NT_W == NTILES, "");
    static_assert(CPB % CHUNKS == 0, "block stays within one batch");
    static_assert(NCIN == 1 || CT == 64, "staging: lane==col");

    __shared__ __bf16 xh_lds[2 * BUF];
    __shared__ __bf16 xl_lds[2 * BUF];

    const int tid  = threadIdx.x;
    const int wave = tid >> 6, lane = tid & 63;
    const int m16  = lane & 15, quad = lane >> 4;

    const int bid    = blockIdx.x;
    const int b      = bid / BPB;
    const int octet  = bid % BPB;
    const int s0base = octet * (CHUNKS * CT);

    // --- NCIN==1 staging helpers (register path, v13) -----------------------
    int sj[SPT], scol[SPT];
    bool sv[SPT];
#pragma unroll
    for (int i = 0; i < SPT; i++) {
        int site = tid + i * NTHR;
        sv[i] = (site < GS);
        int ss = sv[i] ? site : 0;
        sj[i] = ss / CT;
        scol[i] = ss % CT;
    }
    auto stage_site1 = [&](int i, int nn, __bf16* dh, __bf16* dl) {
        float v = prevF[(size_t)b * SITES + nn];
        __bf16 hi = (__bf16)v;
        dh[scol[i] * KSTR + sj[i]] = hi;
        dl[scol[i] * KSTR + sj[i]] = (__bf16)(v - (float)hi);
    };

    // --- NCIN==8 staging: per (j,lane) slot, 16B H + 16B L, write-late ------
    auto stage8 = [&](const int* nnv, __bf16* dh, __bf16* dl) {
        bf16x8 hv[JPW], lv[JPW];
#pragma unroll
        for (int u = 0; u < JPW; u++) {
            int jj = wave + u * NWAVES;
            if (jj < NGB) {
                size_t base = ((size_t)(b * SITES + nnv[u])) * 8;
                hv[u] = *(const bf16x8*)(prevH + base);
                lv[u] = *(const bf16x8*)(prevL + base);
            }
        }
#pragma unroll
        for (int u = 0; u < JPW; u++) {
            int jj = wave + u * NWAVES;
            if (jj < NGB) {
                *(bf16x8*)(dh + (jj * CT + lane) * 8) = hv[u];
                *(bf16x8*)(dl + (jj * CT + lane) * 8) = lv[u];
            }
        }
    };

    // --- zero K-pad of BOTH buffers once ------------------------------------
    if constexpr (NCIN == 1) {
        for (int e = tid; e < 2 * CT * (KPAD - NGB); e += NTHR) {
            int buf = e / (CT * (KPAD - NGB));
            int r   = e % (CT * (KPAD - NGB));
            int col = r / (KPAD - NGB), p = r % (KPAD - NGB);
            xh_lds[buf * BUF + col * KSTR + NGB + p] = (__bf16)0.f;
            xl_lds[buf * BUF + col * KSTR + NGB + p] = (__bf16)0.f;
        }
    } else {
        const bf16x8 z8 = {};
        for (int e = tid; e < 2 * 3 * CT; e += NTHR) {   // j = 13,14,15
            int buf = e / (3 * CT), r = e % (3 * CT);
            *(bf16x8*)(xh_lds + buf * BUF + (13 * CT + r) * 8) = z8;
            *(bf16x8*)(xl_lds + buf * BUF + (13 * CT + r) * 8) = z8;
        }
    }

    // --- prologue: stage chunk 0 into buffer 0; prefetch NN for chunk 1 -----
    int nnA[SPT];     // NCIN==1
    int nnP[JPW];     // NCIN==8
    if constexpr (NCIN == 1) {
#pragma unroll
        for (int i = 0; i < SPT; i++) if (sv[i]) {
            int nn = NN[sj[i] * SITES + s0base + scol[i]];
            stage_site1(i, nn, xh_lds, xl_lds);
        }
        if (CHUNKS > 1) {
            const int s1 = s0base + CT;
#pragma unroll
            for (int i = 0; i < SPT; i++)
                nnA[i] = sv[i] ? NN[sj[i] * SITES + s1 + scol[i]] : 0;
        }
    } else {
        int nn0[JPW];
#pragma unroll
        for (int u = 0; u < JPW; u++) {
            int jj = wave + u * NWAVES;
            nn0[u] = (jj < NGB) ? NN[jj * SITES + s0base + lane] : 0;
        }
        stage8(nn0, xh_lds, xl_lds);
        if (CHUNKS > 1) {
#pragma unroll
            for (int u = 0; u < JPW; u++) {
                int jj = wave + u * NWAVES;
                nnP[u] = (jj < NGB) ? NN[jj * SITES + s0base + CT + lane] : 0;
            }
        }
    }
    __syncthreads();

    const int wave_mt0 = (wave / NWN) * MT_W;
    const int wave_nt0 = (wave % NWN) * NT_W;
    const int o_g      = (wave_mt0 * 16) / NGRP;
    const float bo     = bias[o_g];

#pragma unroll 1
    for (int c = 0; c < CHUNKS; c++) {
        const int cur = c & 1;
        const __bf16* xh = xh_lds + cur * BUF;
        const __bf16* xl = xl_lds + cur * BUF;

        // --- (1) compute chunk c from buffer cur ----------------------------
        f32x4 acc[MT_W][NT_W];
#pragma unroll
        for (int mt = 0; mt < MT_W; mt++)
#pragma unroll
            for (int nt = 0; nt < NT_W; nt++) acc[mt][nt] = (f32x4){0.f, 0.f, 0.f, 0.f};

#pragma unroll
        for (int kt = 0; kt < KT; kt++) {
            const int koff = kt * 32 + quad * 8;
            bf16x8 ah[MT_W], al[MT_W], bh[NT_W], bl[NT_W];
#pragma unroll
            for (int mt = 0; mt < MT_W; mt++) {
                int row = (wave_mt0 + mt) * 16 + m16;
                ah[mt] = *(const bf16x8*)(Wh + (size_t)row * KPAD + koff);
                al[mt] = *(const bf16x8*)(Wl + (size_t)row * KPAD + koff);
            }
#pragma unroll
            for (int nt = 0; nt < NT_W; nt++) {
                int cbase;
                if constexpr (NCIN == 1)
                    cbase = ((wave_nt0 + nt) * 16 + m16) * KSTR + koff;
                else
                    cbase = ((kt * 4 + quad) * CT + (wave_nt0 + nt) * 16 + m16) * 8;
                bh[nt] = *(const bf16x8*)(xh + cbase);
                bl[nt] = *(const bf16x8*)(xl + cbase);
            }
            // product-major: 12 independent MFMAs between same-acc reuse
#pragma unroll
            for (int mt = 0; mt < MT_W; mt++)
#pragma unroll
                for (int nt = 0; nt < NT_W; nt++)
                    acc[mt][nt] = __builtin_amdgcn_mfma_f32_16x16x32_bf16(
                        ah[mt], bh[nt], acc[mt][nt], 0, 0, 0);
#pragma unroll
            for (int mt = 0; mt < MT_W; mt++)
#pragma unroll
                for (int nt = 0; nt < NT_W; nt++)
                    acc[mt][nt] = __builtin_amdgcn_mfma_f32_16x16x32_bf16(
                        al[mt], bh[nt], acc[mt][nt], 0, 0, 0);
#pragma unroll
            for (int mt = 0; mt < MT_W; mt++)
#pragma unroll
                for (int nt = 0; nt < NT_W; nt++)
                    acc[mt][nt] = __builtin_amdgcn_mfma_f32_16x16x32_bf16(
                        ah[mt], bl[nt], acc[mt][nt], 0, 0, 0);
        }

        // --- (2) epilogue: softplus + group mean (one o per wave) -----------
        const int s0c = s0base + c * CT;
#pragma unroll
        for (int nt = 0; nt < NT_W; nt++) {
            float s = 0.f;
#pragma unroll
            for (int mt = 0; mt < MT_W; mt++)
#pragma unroll
                for (int r = 0; r < 4; r++)
                    s += softplus_f(acc[mt][nt][r] + bo);
            s += __shfl_xor(s, 16);
            s += __shfl_xor(s, 32);
            if (quad == 0) {
                float sv2 = s * (1.f / 48.f);
                size_t idx = (size_t)(b * SITES + s0c + (wave_nt0 + nt) * 16 + m16);
                if constexpr (OUTF32) {
                    outF[idx] = sv2;
                } else {
                    __bf16 hi = (__bf16)sv2;
                    outH[idx * NCTOT + o_g] = hi;
                    outL[idx * NCTOT + o_g] = (__bf16)(sv2 - (float)hi);
                }
            }
        }

        // --- (3) stage chunk c+1 into buffer cur^1 (late, v13 ordering) -----
        if (c + 1 < CHUNKS) {
            __bf16* dh = xh_lds + (cur ^ 1) * BUF;
            __bf16* dl = xl_lds + (cur ^ 1) * BUF;
            if constexpr (NCIN == 1) {
#pragma unroll
                for (int i = 0; i < SPT; i++) if (sv[i])
                    stage_site1(i, nnA[i], dh, dl);
                if (c + 2 < CHUNKS) {
                    const int s2 = s0base + (c + 2) * CT;
#pragma unroll
                    for (int i = 0; i < SPT; i++)
                        nnA[i] = sv[i] ? NN[sj[i] * SITES + s2 + scol[i]] : 0;
                }
            } else {
                stage8(nnP, dh, dl);
                if (c + 2 < CHUNKS) {
                    const int s2 = s0base + (c + 2) * CT;
#pragma unroll
                    for (int u = 0; u < JPW; u++) {
                        int jj = wave + u * NWAVES;
                        nnP[u] = (jj < NGB) ? NN[jj * SITES + s2 + lane] : 0;
                    }
                }
            }
        }
        __syncthreads();
    }
}

// ---------------------------------------------------------------------------
// Reduce stage A: per (b, s-chunk) block -> 3 partial sums
// ---------------------------------------------------------------------------
__global__ __launch_bounds__(256) void reduce_a(
    const float* __restrict__ A2, const int* __restrict__ NN,
    const int* __restrict__ s2sh, const float* __restrict__ sw,
    const float* __restrict__ Avc, float* __restrict__ partial)
{
    const int b = blockIdx.x >> 4;
    const int chunk = blockIdx.x & 15;
    const int tid = threadIdx.x;
    const int s = (chunk << 8) + tid;
    const float* a = A2 + (size_t)b * SITES;

    float y0 = 0.f, y1 = 0.f, y2 = 0.f;
#pragma unroll
    for (int n = 0; n < NGB; n++) {
        float v = a[NN[n * SITES + s]];
        y0 = fmaf(Avc[n],           v, y0);
        y1 = fmaf(Avc[NGB + n],     v, y1);
        y2 = fmaf(Avc[2 * NGB + n], v, y2);
    }
    const float wgt = sw[s2sh[s]];
    y0 *= wgt; y1 *= wgt; y2 *= wgt;

    __shared__ float red[3][256];
    red[0][tid] = y0; red[1][tid] = y1; red[2][tid] = y2;
    __syncthreads();
    for (int st = 128; st > 0; st >>= 1) {
        if (tid < st) {
            red[0][tid] += red[0][tid + st];
            red[1][tid] += red[1][tid + st];
            red[2][tid] += red[2][tid + st];
        }
        __syncthreads();
    }
    if (tid < 3) partial[(b * 16 + chunk) * 3 + tid] = red[tid][0];
}

__global__ __launch_bounds__(256) void reduce_b(
    const float* __restrict__ partial, float* __restrict__ out)
{
    int t = threadIdx.x;
    if (t < BATCH * 3) {
        int b = t / 3, d = t - b * 3;
        float s = 0.f;
        for (int c = 0; c < 16; c++) s += partial[(b * 16 + c) * 3 + d];
        out[t] = s * (1.f / (float)SITES);
    }
}

// ---------------------------------------------------------------------------
extern "C" void kernel_launch(void* const* d_in, const int* in_sizes, int n_in,
                              void* d_out, int out_size, void* d_ws, size_t ws_size,
                              hipStream_t stream)
{
    const float* InStates = (const float*)d_in[0];
    const float* Psi0     = (const float*)d_in[1];
    const float* bias0    = (const float*)d_in[2];
    const float* Psi1     = (const float*)d_in[3];
    const float* bias1    = (const float*)d_in[4];
    const float* Psi2     = (const float*)d_in[5];
    const float* bias2    = (const float*)d_in[6];
    const float* wtVC     = (const float*)d_in[7];
    const float* ShellW   = (const float*)d_in[8];
    const float* gdiags   = (const float*)d_in[9];
    const int*   GnnPerms = (const int*)d_in[10];
    const int*   NNSites  = (const int*)d_in[11];
    const int*   S2Sh     = (const int*)d_in[12];

    float*  ws   = (float*)d_ws;
    float*  Avc  = ws + OFF_AVC;
    __bf16* U    = (__bf16*)(ws + OFF_U);
    __bf16* A0H  = (__bf16*)(ws + OFF_A0H);
    __bf16* A0L  = (__bf16*)(ws + OFF_A0L);
    __bf16* A1H  = (__bf16*)(ws + OFF_A1H);
    __bf16* A1L  = (__bf16*)(ws + OFF_A1L);
    float*  A2   = ws + OFF_A0H;     // f32 (B,S): A0 dead once L2 runs
    float*  PART = ws + OFF_PART;

    float* out = (float*)d_out;      // (64,3) f32

    hipMemsetAsync(Avc, 0, 64 * sizeof(float), stream);
    precompute_kernel<<<272, 256, 0, stream>>>(Psi0, Psi1, Psi2, wtVC, gdiags,
                                               GnnPerms, ws);

    constexpr int CHUNKS = 8;
    constexpr int NBLK   = BATCH * (SITES / 64) / CHUNKS;   // 512 blocks

    // L0: K=13 pad 32, KSTR=40; f32 in, hi/lo bf16 out
    layer_mfma<1, 8, 0, 64, 32, 40, 8, 1, CHUNKS><<<NBLK, 512, 0, stream>>>(
        InStates, nullptr, nullptr, U + UW0H, U + UW0L, bias0, NNSites,
        nullptr, A0H, A0L);
    // L1: K=104 pad 128; hi/lo in (register-staged late), hi/lo out
    layer_mfma<8, 8, 0, 64, 128, 136, 8, 1, CHUNKS><<<NBLK, 512, 0, stream>>>(
        nullptr, A0H, A0L, U + UW1H, U + UW1L, bias1, NNSites,
        nullptr, A1H, A1L);
    // L2: K=104 pad 128, M=48 (1 o), 4 waves split cols; f32 out
    layer_mfma<8, 1, 1, 64, 128, 136, 4, 4, CHUNKS><<<NBLK, 256, 0, stream>>>(
        nullptr, A1H, A1L, U + UW2H, U + UW2L, bias2, NNSites,
        A2, nullptr, nullptr);

    reduce_a<<<BATCH * 16, 256, 0, stream>>>(A2, NNSites, S2Sh, ShellW, Avc, PART);
    reduce_b<<<1, 256, 0, stream>>>(PART, out);
}

// Round 7
// 331.713 us; speedup vs baseline: 1.0880x; 1.0680x over previous
//
#include <hip/hip_runtime.h>
#include <hip/hip_bf16.h>

// Problem constants (SymNetDP): B=64, S=4096, NGB=13, NG=48, DIM=3, NCH={8,8,1}
#define BATCH 64
#define SITES 4096
#define NGB 13
#define NGRP 48
#define SDIM 3

typedef __bf16 bf16x8 __attribute__((ext_vector_type(8)));
typedef float  f32x4  __attribute__((ext_vector_type(4)));

// ---------------------------------------------------------------------------
// Workspace layout (v13 storage: f32 activations):
//   Avc  : 39 f32 (pad 64)                      @ float 0
//   U    : bf16 region, 135168 elems            @ float 64
//     W0H [384][32] 12288 | W0L @12288 | W1H [384][128] @24576 (49152) |
//     W1L @73728 | W2H [48][128] @122880 (6144) | W2L @129024
//   A0   : (B,S,8) channel-last f32             @ float 67648  (A2 aliases)
//   A1   : (B,S,8) channel-last f32             @ float 2164800
//   PART : (64,16,3)                            @ float 4261952
// K-packing for NCIN=8 layers: k = j*8 + c  (site's 8 channels contiguous).
//
// v17 = v13 + intra-wave stage/compute interleave.
// Post-mortems: v15/v16 layout + hi/lo-global experiments were neutral-to-
// negative (bank conflicts were the free 2-way kind; hi/lo 2B streams hurt
// write coalescing) -> reverted to v13 storage. v13's remaining ~60us of L1
// is exposed gather latency (MFMA busy 32us, true VALU ~25us, occupancy
// VGPR+LDS capped). v17 splits each thread's SPT stage slots across the 4
// unrolled kt iterations of the NEXT-chunk prefetch: kt0/kt1 issue 32B
// gather loads, kt2/kt3 cvt+ds_write into the free buffer. Peak extra
// liveness 16 VGPR (L1) for ~2 kt of MFMA -> no spill (v10's failure was
// the forced-64-VGPR cap holding state across the WHOLE compute).
// ---------------------------------------------------------------------------
#define OFF_AVC  0
#define OFF_U    64
#define OFF_A0   67648
#define OFF_A1   2164800
#define OFF_PART 4261952
#define UW0H 0
#define UW0L 12288
#define UW1H 24576
#define UW1L 73728
#define UW2H 122880
#define UW2L 129024

__device__ __forceinline__ float softplus_f(float h) {
    return fmaxf(h, 0.f) + __logf(1.f + __expf(-fabsf(h)));
}

// ---------------------------------------------------------------------------
// Precompute: rotated weights, bf16 hi/lo split, [row=o*48+g][KPAD] with
// k = j*8+c packing for K=104 layers (k = j for layer 0); plus Avc.
// ---------------------------------------------------------------------------
__global__ __launch_bounds__(256) void precompute_kernel(
    const float* __restrict__ Psi0, const float* __restrict__ Psi1,
    const float* __restrict__ Psi2, const float* __restrict__ wtVC,
    const float* __restrict__ gdiags, const int* __restrict__ perms,
    float* __restrict__ ws)
{
    float*  Avc = ws + OFF_AVC;
    __bf16* U   = (__bf16*)(ws + OFF_U);
    int t = blockIdx.x * 256 + threadIdx.x;
    if (t < 12288) {                       // W0: [384][32], k=j
        int k = t & 31, row = t >> 5;
        int o = row / NGRP, g = row - o * NGRP;
        float w = (k < NGB) ? Psi0[o * NGB + perms[g * NGB + k]] : 0.f;
        __bf16 hi = (__bf16)w;
        U[UW0H + t] = hi;
        U[UW0L + t] = (__bf16)(w - (float)hi);
    } else if (t < 61440) {                // W1: [384][128], k=j*8+c
        int u = t - 12288;
        int k = u & 127, row = u >> 7;
        int o = row / NGRP, g = row - o * NGRP;
        float w = 0.f;
        if (k < 104) { int j = k >> 3, c = k & 7;
                       w = Psi1[(o * 8 + c) * NGB + perms[g * NGB + j]]; }
        __bf16 hi = (__bf16)w;
        U[UW1H + u] = hi;
        U[UW1L + u] = (__bf16)(w - (float)hi);
    } else if (t < 67584) {                // W2: [48][128], k=j*8+c
        int u = t - 61440;
        int k = u & 127, g = u >> 7;
        float w = 0.f;
        if (k < 104) { int j = k >> 3, c = k & 7;
                       w = Psi2[c * NGB + perms[g * NGB + j]]; }
        __bf16 hi = (__bf16)w;
        U[UW2H + u] = hi;
        U[UW2L + u] = (__bf16)(w - (float)hi);
    } else if (t < 67584 + 39 * NGRP) {    // Avc
        int t2 = t - 67584;
        int g = t2 % NGRP, u = t2 / NGRP;
        int d = u / NGB, n = u % NGB;
        const int row = g * SDIM + d;
        float s = 0.f;
        for (int k = 0; k < NGRP * SDIM; k++) {
            int g2 = k / SDIM, d2 = k - g2 * SDIM;
            float p = wtVC[d2 * NGB + perms[g2 * NGB + n]];
            s = fmaf(gdiags[row * (NGRP * SDIM) + k], p, s);
        }
        atomicAdd(&Avc[u], s * (1.f / 48.f));
    }
}

// ---------------------------------------------------------------------------
// MFMA gconv layer (bf16x3 split), v17: persistent-lite + interleaved stage.
// NCIN==8: next-chunk staging split across the unrolled kt loop:
//   kt in [0, KT/2):   issue 32B gather loads for slot subset (nnA indices)
//   kt in [KT/2, KT):  cvt hi/lo + ds_write_b128 the same subset
// Registers live <= 2 kt iterations (~1400 MFMA cycles) -> covers L2/HBM
// gather latency without long-lived state (no spill).
// NCIN==1 (L0, KT=1): v13 late-stage path.
// ---------------------------------------------------------------------------
template<int NCIN, int NCTOT, int CT, int KPAD, int KSTR, int NWAVES, int NWN,
         int CHUNKS>
__global__ __launch_bounds__(NWAVES * 64) void layer_mfma(
    const float* __restrict__ prev,   // (B,S) if NCIN==1 else (B,S,8)
    const __bf16* __restrict__ Wh,    // [NCTOT*48][KPAD]
    const __bf16* __restrict__ Wl,
    const float* __restrict__ bias,   // (NCTOT,)
    const int*   __restrict__ NN,     // (13, S)
    float* __restrict__ out)          // (B,S,NCTOT) channel-last
{
    constexpr int NTHR   = NWAVES * 64;
    constexpr int M      = NCTOT * NGRP;
    constexpr int MTILES = M / 16, NTILES = CT / 16;
    constexpr int NWM    = NWAVES / NWN;
    constexpr int MT_W   = MTILES / NWM, NT_W = NTILES / NWN;
    constexpr int KT     = KPAD / 32;
    constexpr int GS     = NGB * CT;              // gathered sites per chunk
    constexpr int SPT    = (GS + NTHR - 1) / NTHR;
    constexpr int CPB    = SITES / CT;            // chunks per batch
    constexpr int BUF    = CT * KSTR;             // halfwords per LDS buffer
    constexpr int BPB    = CPB / CHUNKS;          // blocks per batch
    constexpr int LKT    = (KT >= 2) ? KT / 2 : 1;
    constexpr int SPW    = (SPT + LKT - 1) / LKT; // slots per stage-kt

    static_assert(MT_W * 16 == NGRP, "wave covers exactly one o");
    static_assert(NWM * MT_W == MTILES && NWN * NT_W == NTILES, "");
    static_assert((KPAD & 31) == 0 && (KSTR & 7) == 0, "");
    static_assert(CPB % CHUNKS == 0, "block stays within one batch");

    __shared__ __bf16 xh_lds[2 * BUF];
    __shared__ __bf16 xl_lds[2 * BUF];

    const int tid  = threadIdx.x;
    const int wave = tid >> 6, lane = tid & 63;
    const int m16  = lane & 15, quad = lane >> 4;

    const int bid    = blockIdx.x;
    const int b      = bid / BPB;
    const int octet  = bid % BPB;
    const int s0base = octet * (CHUNKS * CT);

    // --- per-thread staged-site slots (static decomposition) ----------------
    int sj[SPT], scol[SPT];
    bool sv[SPT];
#pragma unroll
    for (int i = 0; i < SPT; i++) {
        int site = tid + i * NTHR;
        sv[i] = (site < GS);
        int ss = sv[i] ? site : 0;
        sj[i] = ss / CT;
        scol[i] = ss % CT;
    }

    // staged-load registers (short-lived: filled kt<LKT, drained kt>=LKT)
    float4 ga[SPT], gb[SPT];
    float  g1[SPT];

    auto ld8 = [&](int i, int nn) {
        const float4* p4 = (const float4*)(prev + ((size_t)(b * SITES + nn)) * 8);
        ga[i] = p4[0];
        gb[i] = p4[1];
    };
    auto wr8 = [&](int i, __bf16* dh, __bf16* dl) {
        float v[8] = {ga[i].x, ga[i].y, ga[i].z, ga[i].w,
                      gb[i].x, gb[i].y, gb[i].z, gb[i].w};
        bf16x8 hv, lv;
#pragma unroll
        for (int c8 = 0; c8 < 8; c8++) {
            __bf16 hi = (__bf16)v[c8];
            hv[c8] = hi;
            lv[c8] = (__bf16)(v[c8] - (float)hi);
        }
        *(bf16x8*)(dh + scol[i] * KSTR + sj[i] * 8) = hv;
        *(bf16x8*)(dl + scol[i] * KSTR + sj[i] * 8) = lv;
    };
    auto stage_site1 = [&](int i, int nn, __bf16* dh, __bf16* dl) {
        float v = prev[(size_t)b * SITES + nn];
        __bf16 hi = (__bf16)v;
        dh[scol[i] * KSTR + sj[i]] = hi;
        dl[scol[i] * KSTR + sj[i]] = (__bf16)(v - (float)hi);
    };

    // --- zero the K-pad region of BOTH buffers once -------------------------
    if constexpr (NCIN == 1) {
        for (int e = tid; e < 2 * CT * (KPAD - NGB); e += NTHR) {
            int buf = e / (CT * (KPAD - NGB));
            int r   = e % (CT * (KPAD - NGB));
            int col = r / (KPAD - NGB), p = r % (KPAD - NGB);
            xh_lds[buf * BUF + col * KSTR + NGB + p] = (__bf16)0.f;
            xl_lds[buf * BUF + col * KSTR + NGB + p] = (__bf16)0.f;
        }
    } else {
        const bf16x8 z8 = {};
        for (int e = tid; e < 2 * CT * 3; e += NTHR) {
            int buf = e / (CT * 3);
            int r   = e % (CT * 3);
            int col = r % CT, z = r / CT;
            *(bf16x8*)(xh_lds + buf * BUF + col * KSTR + 104 + z * 8) = z8;
            *(bf16x8*)(xl_lds + buf * BUF + col * KSTR + 104 + z * 8) = z8;
        }
    }

    // --- prologue: stage chunk 0 into buffer 0; prefetch NN for chunk 1 -----
    int nnA[SPT];
#pragma unroll
    for (int i = 0; i < SPT; i++) if (sv[i]) {
        int nn = NN[sj[i] * SITES + s0base + scol[i]];
        if constexpr (NCIN == 1) {
            stage_site1(i, nn, xh_lds, xl_lds);
        } else {
            ld8(i, nn);
            wr8(i, xh_lds, xl_lds);
        }
    }
    if (CHUNKS > 1) {
        const int s1 = s0base + CT;
#pragma unroll
        for (int i = 0; i < SPT; i++)
            nnA[i] = sv[i] ? NN[sj[i] * SITES + s1 + scol[i]] : 0;
    }
    __syncthreads();

    const int wave_mt0 = (wave / NWN) * MT_W;
    const int wave_nt0 = (wave % NWN) * NT_W;
    const int o_g      = (wave_mt0 * 16) / NGRP;
    const float bo     = bias[o_g];

#pragma unroll 1
    for (int c = 0; c < CHUNKS; c++) {
        const int cur = c & 1;
        const __bf16* xh = xh_lds + cur * BUF;
        const __bf16* xl = xl_lds + cur * BUF;
        __bf16* dh = xh_lds + (cur ^ 1) * BUF;
        __bf16* dl = xl_lds + (cur ^ 1) * BUF;
        const bool do_stage = (c + 1 < CHUNKS);

        // --- compute chunk c, with next-chunk staging interleaved -----------
        f32x4 acc[MT_W][NT_W];
#pragma unroll
        for (int mt = 0; mt < MT_W; mt++)
#pragma unroll
            for (int nt = 0; nt < NT_W; nt++) acc[mt][nt] = (f32x4){0.f, 0.f, 0.f, 0.f};

#pragma unroll
        for (int kt = 0; kt < KT; kt++) {
            const int koff = kt * 32 + quad * 8;
            bf16x8 ah[MT_W], al[MT_W], bh[NT_W], bl[NT_W];
#pragma unroll
            for (int mt = 0; mt < MT_W; mt++) {
                int row = (wave_mt0 + mt) * 16 + m16;
                ah[mt] = *(const bf16x8*)(Wh + (size_t)row * KPAD + koff);
                al[mt] = *(const bf16x8*)(Wl + (size_t)row * KPAD + koff);
            }
#pragma unroll
            for (int nt = 0; nt < NT_W; nt++) {
                int cbase = ((wave_nt0 + nt) * 16 + m16) * KSTR + koff;
                bh[nt] = *(const bf16x8*)(xh + cbase);
                bl[nt] = *(const bf16x8*)(xl + cbase);
            }
            // product-major: 12 independent MFMAs between same-acc reuse
#pragma unroll
            for (int mt = 0; mt < MT_W; mt++)
#pragma unroll
                for (int nt = 0; nt < NT_W; nt++)
                    acc[mt][nt] = __builtin_amdgcn_mfma_f32_16x16x32_bf16(
                        ah[mt], bh[nt], acc[mt][nt], 0, 0, 0);
#pragma unroll
            for (int mt = 0; mt < MT_W; mt++)
#pragma unroll
                for (int nt = 0; nt < NT_W; nt++)
                    acc[mt][nt] = __builtin_amdgcn_mfma_f32_16x16x32_bf16(
                        al[mt], bh[nt], acc[mt][nt], 0, 0, 0);
#pragma unroll
            for (int mt = 0; mt < MT_W; mt++)
#pragma unroll
                for (int nt = 0; nt < NT_W; nt++)
                    acc[mt][nt] = __builtin_amdgcn_mfma_f32_16x16x32_bf16(
                        ah[mt], bl[nt], acc[mt][nt], 0, 0, 0);

            // --- staged piece for chunk c+1 (NCIN==8, KT>=2) ----------------
            if constexpr (NCIN == 8 && KT >= 2) {
                if (do_stage) {
                    if (kt < LKT) {
#pragma unroll
                        for (int u = 0; u < SPW; u++) {
                            constexpr int dummy = 0; (void)dummy;
                            int i = kt * SPW + u;
                            if (i < SPT && sv[i]) ld8(i, nnA[i]);
                        }
                    } else {
#pragma unroll
                        for (int u = 0; u < SPW; u++) {
                            int i = (kt - LKT) * SPW + u;
                            if (i < SPT && sv[i]) wr8(i, dh, dl);
                        }
                    }
                }
            }
        }

        // --- NN prefetch for chunk c+2 (latency hidden by epilogue) ---------
        if constexpr (NCIN == 8) {
            if (c + 2 < CHUNKS) {
                const int s2 = s0base + (c + 2) * CT;
#pragma unroll
                for (int i = 0; i < SPT; i++)
                    nnA[i] = sv[i] ? NN[sj[i] * SITES + s2 + scol[i]] : 0;
            }
        }

        // --- epilogue: softplus + group mean (one o per wave) ---------------
        const int s0c = s0base + c * CT;
#pragma unroll
        for (int nt = 0; nt < NT_W; nt++) {
            float s = 0.f;
#pragma unroll
            for (int mt = 0; mt < MT_W; mt++)
#pragma unroll
                for (int r = 0; r < 4; r++)
                    s += softplus_f(acc[mt][nt][r] + bo);
            s += __shfl_xor(s, 16);
            s += __shfl_xor(s, 32);
            if (quad == 0)
                out[((size_t)(b * SITES + s0c + (wave_nt0 + nt) * 16 + m16)) * NCTOT + o_g]
                    = s * (1.f / 48.f);
        }

        // --- NCIN==1 (KT==1): late stage path (v13) -------------------------
        if constexpr (NCIN == 1) {
            if (do_stage) {
#pragma unroll
                for (int i = 0; i < SPT; i++) if (sv[i])
                    stage_site1(i, nnA[i], dh, dl);
                if (c + 2 < CHUNKS) {
                    const int s2 = s0base + (c + 2) * CT;
#pragma unroll
                    for (int i = 0; i < SPT; i++)
                        nnA[i] = sv[i] ? NN[sj[i] * SITES + s2 + scol[i]] : 0;
                }
            }
        }
        __syncthreads();
    }
}

// ---------------------------------------------------------------------------
// Reduce stage A: per (b, s-chunk) block -> 3 partial sums
// ---------------------------------------------------------------------------
__global__ __launch_bounds__(256) void reduce_a(
    const float* __restrict__ A2, const int* __restrict__ NN,
    const int* __restrict__ s2sh, const float* __restrict__ sw,
    const float* __restrict__ Avc, float* __restrict__ partial)
{
    const int b = blockIdx.x >> 4;
    const int chunk = blockIdx.x & 15;
    const int tid = threadIdx.x;
    const int s = (chunk << 8) + tid;
    const float* a = A2 + (size_t)b * SITES;

    float y0 = 0.f, y1 = 0.f, y2 = 0.f;
#pragma unroll
    for (int n = 0; n < NGB; n++) {
        float v = a[NN[n * SITES + s]];
        y0 = fmaf(Avc[n],           v, y0);
        y1 = fmaf(Avc[NGB + n],     v, y1);
        y2 = fmaf(Avc[2 * NGB + n], v, y2);
    }
    const float wgt = sw[s2sh[s]];
    y0 *= wgt; y1 *= wgt; y2 *= wgt;

    __shared__ float red[3][256];
    red[0][tid] = y0; red[1][tid] = y1; red[2][tid] = y2;
    __syncthreads();
    for (int st = 128; st > 0; st >>= 1) {
        if (tid < st) {
            red[0][tid] += red[0][tid + st];
            red[1][tid] += red[1][tid + st];
            red[2][tid] += red[2][tid + st];
        }
        __syncthreads();
    }
    if (tid < 3) partial[(b * 16 + chunk) * 3 + tid] = red[tid][0];
}

__global__ __launch_bounds__(256) void reduce_b(
    const float* __restrict__ partial, float* __restrict__ out)
{
    int t = threadIdx.x;
    if (t < BATCH * 3) {
        int b = t / 3, d = t - b * 3;
        float s = 0.f;
        for (int c = 0; c < 16; c++) s += partial[(b * 16 + c) * 3 + d];
        out[t] = s * (1.f / (float)SITES);
    }
}

// ---------------------------------------------------------------------------
extern "C" void kernel_launch(void* const* d_in, const int* in_sizes, int n_in,
                              void* d_out, int out_size, void* d_ws, size_t ws_size,
                              hipStream_t stream)
{
    const float* InStates = (const float*)d_in[0];
    const float* Psi0     = (const float*)d_in[1];
    const float* bias0    = (const float*)d_in[2];
    const float* Psi1     = (const float*)d_in[3];
    const float* bias1    = (const float*)d_in[4];
    const float* Psi2     = (const float*)d_in[5];
    const float* bias2    = (const float*)d_in[6];
    const float* wtVC     = (const float*)d_in[7];
    const float* ShellW   = (const float*)d_in[8];
    const float* gdiags   = (const float*)d_in[9];
    const int*   GnnPerms = (const int*)d_in[10];
    const int*   NNSites  = (const int*)d_in[11];
    const int*   S2Sh     = (const int*)d_in[12];

    float*  ws   = (float*)d_ws;
    float*  Avc  = ws + OFF_AVC;
    __bf16* U    = (__bf16*)(ws + OFF_U);
    float*  A0   = ws + OFF_A0;      // (B,S,8) channel-last
    float*  A1   = ws + OFF_A1;      // (B,S,8) channel-last
    float*  A2   = ws + OFF_A0;      // (B,S) alias: A0 dead once L2 runs
    float*  PART = ws + OFF_PART;

    float* out = (float*)d_out;      // (64,3) f32

    hipMemsetAsync(Avc, 0, 64 * sizeof(float), stream);
    precompute_kernel<<<272, 256, 0, stream>>>(Psi0, Psi1, Psi2, wtVC, gdiags,
                                               GnnPerms, ws);

    constexpr int CHUNKS = 8;
    constexpr int NBLK   = BATCH * (SITES / 64) / CHUNKS;   // 512 blocks

    // L0: K=13 pad 32, KSTR=40 (80B rows, stride 20 words -> 2-way free)
    layer_mfma<1, 8, 64, 32, 40, 8, 1, CHUNKS><<<NBLK, 512, 0, stream>>>(
        InStates, U + UW0H, U + UW0L, bias0, NNSites, A0);
    // L1: K=104 pad 128, KSTR=136 (272B rows, stride 68 words -> 2-way free)
    layer_mfma<8, 8, 64, 128, 136, 8, 1, CHUNKS><<<NBLK, 512, 0, stream>>>(
        A0, U + UW1H, U + UW1L, bias1, NNSites, A1);
    // L2: K=104 pad 128, M=48 (1 o), 4 waves split cols
    layer_mfma<8, 1, 64, 128, 136, 4, 4, CHUNKS><<<NBLK, 256, 0, stream>>>(
        A1, U + UW2H, U + UW2L, bias2, NNSites, A2);

    reduce_a<<<BATCH * 16, 256, 0, stream>>>(A2, NNSites, S2Sh, ShellW, Avc, PART);
    reduce_b<<<1, 256, 0, stream>>>(PART, out);
}